// Round 10
// baseline (245.160 us; speedup 1.0000x reference)
//
#include <hip/hip_runtime.h>
#include <hip/hip_bf16.h>
#include <stdint.h>

#define T_TOK 2048
#define HDIM  1024
#define IDIM  768
#define NEXP  32
#define TOPK  4
#define NPAIR (T_TOK*TOPK)   // 8192
#define MTILE 384
#define MAXMT 64

typedef __attribute__((ext_vector_type(8))) short bf16x8;
typedef __attribute__((ext_vector_type(4))) float f32x4;

typedef __attribute__((address_space(1))) const unsigned int gu32;
typedef __attribute__((address_space(3))) unsigned int lu32;

__device__ __forceinline__ void gload_lds16(const void* g, void* l){
  __builtin_amdgcn_global_load_lds((gu32*)g, (lu32*)l, 16, 0, 0);
}

#define WAITV(n) asm volatile("s_waitcnt vmcnt(" #n ")" ::: "memory")
#define CFENCE() asm volatile("" ::: "memory")

__device__ __forceinline__ unsigned short f2bf(float f){
  union { float f; unsigned u; } v; v.f = f;
  unsigned r = (v.u + 0x7fffu + ((v.u >> 16) & 1u)) >> 16;  // RNE
  return (unsigned short)r;
}

__device__ __forceinline__ unsigned pack_bf2(float lo, float hi){
  __hip_bfloat162 h2 = __float22bfloat162_rn(float2{lo, hi});  // v_cvt_pk_bf16_f32
  union { __hip_bfloat162 h; unsigned u; } v; v.h = h2;
  return v.u;
}

// ---------------- x fp32 -> bf16 ----------------
__global__ __launch_bounds__(256) void k_convert_x(const float* __restrict__ x,
                                                   ushort* __restrict__ xb){
  int idx = blockIdx.x*256 + threadIdx.x;
  float4 v = ((const float4*)x)[idx];
  ushort4 o; o.x=f2bf(v.x); o.y=f2bf(v.y); o.z=f2bf(v.z); o.w=f2bf(v.w);
  ((ushort4*)xb)[idx] = o;
}

// ---------------- router ----------------
__global__ __launch_bounds__(256) void k_router(const float* __restrict__ x,
                                                const float* __restrict__ gw,
                                                int* __restrict__ ei, float* __restrict__ wv,
                                                int* __restrict__ counts){
  int wid  = threadIdx.x >> 6;
  int lane = threadIdx.x & 63;
  int t = blockIdx.x*4 + wid;
  float xv[16];
  #pragma unroll
  for (int i=0;i<16;i++) xv[i] = x[t*HDIM + i*64 + lane];
  float p[NEXP];
  #pragma unroll
  for (int e=0;e<NEXP;e++){
    const float* w = gw + e*HDIM;
    float a = 0.f;
    #pragma unroll
    for (int i=0;i<16;i++) a = fmaf(xv[i], w[i*64+lane], a);
    #pragma unroll
    for (int off=32; off>=1; off>>=1) a += __shfl_xor(a, off, 64);
    p[e] = a;
  }
  float m = p[0];
  #pragma unroll
  for (int e=1;e<NEXP;e++) m = fmaxf(m, p[e]);
  #pragma unroll
  for (int e=0;e<NEXP;e++) p[e] = __expf(p[e]-m);
  unsigned used = 0; int sel[TOPK]; float sw[TOPK]; float wsum = 0.f;
  #pragma unroll
  for (int k=0;k<TOPK;k++){
    float best = -1.f; int bi = 0;
    #pragma unroll
    for (int e=0;e<NEXP;e++){
      bool ok = (((used>>e)&1u)==0u) && (p[e] > best);
      best = ok ? p[e] : best; bi = ok ? e : bi;
    }
    used |= 1u<<bi; sel[k]=bi; sw[k]=best; wsum += best;
  }
  if (lane==0){
    float inv = 1.f/wsum;
    #pragma unroll
    for (int k=0;k<TOPK;k++){
      ei[t*TOPK+k] = sel[k];
      wv[t*TOPK+k] = sw[k]*inv;
      atomicAdd(&counts[sel[k]], 1);
    }
  }
}

// ---------------- offsets + m-tile worklist ----------------
__global__ void k_offsets(const int* __restrict__ counts, int* __restrict__ offsets,
                          int* __restrict__ mtE, int* __restrict__ mtM0,
                          int* __restrict__ nmt){
  if (threadIdx.x==0 && blockIdx.x==0){
    int s=0;
    for (int e=0;e<NEXP;e++){ offsets[e]=s; s+=counts[e]; }
    offsets[NEXP]=s;
    int nm=0;
    for (int e=0;e<NEXP;e++){
      int ne = counts[e];
      for (int m0=0; m0<ne && nm<MAXMT; m0+=MTILE){ mtE[nm]=e; mtM0[nm]=m0; nm++; }
    }
    nmt[0]=nm;
  }
}

__global__ __launch_bounds__(256) void k_scatter(const int* __restrict__ ei,
                                                 const int* __restrict__ offsets,
                                                 int* __restrict__ cursor,
                                                 int* __restrict__ slot_tk,
                                                 int* __restrict__ tk_slot){
  int g = blockIdx.x*256 + threadIdx.x;
  int e = ei[g];
  int pos = atomicAdd(&cursor[e], 1);
  int slot = offsets[e] + pos;
  slot_tk[slot] = g;
  tk_slot[g] = slot;
}

// ---------------- gate+up GEMM + SiLU ----------------
// M=384 x N=32 (x2 mats). K=1024 = 32 ring slots of 32.
// 448 threads: wave 6 = producer (DMA into 8-deep LDS ring, counted vmcnt,
// LDS flag publish), waves 0-5 = consumers (64 rows each, A direct-global,
// B from ring w/ XOR swizzle + cvt_pk). NO barriers in the main loop.
__global__ __launch_bounds__(448,4) void k_gateup(const ushort* __restrict__ xb,
    const float* __restrict__ w1, const float* __restrict__ w3,
    const int* __restrict__ offsets, const int* __restrict__ slot_tk,
    const int* __restrict__ mtE, const int* __restrict__ mtM0, const int* __restrict__ nmt,
    ushort* __restrict__ act){
  const int NS = 32;
  int bi  = blockIdx.x;               // 1536
  int xcd = bi & 7, j0 = bi >> 3;
  int mti = (j0/24)*8 + xcd;
  int it  = j0 % 24;
  if (mti >= nmt[0]) return;
  int e    = mtE[mti];
  int m0   = mtM0[mti];
  int off0 = offsets[e];
  int ne   = offsets[e+1]-off0;
  int ibase = it*32;

  __shared__ float ring[8][64][32];   // [slot][mat*32+row][k f32, src-swizzled]
  __shared__ int toks[MTILE];
  __shared__ int flags[8];
  __shared__ int done[8];

  int tid = threadIdx.x, wid = tid>>6, lane = tid&63;
  if (tid < MTILE){
    int slot = off0 + m0 + tid;
    int fb = slot_tk[off0] >> 2;
    toks[tid] = (m0 + tid < ne) ? (slot_tk[slot] >> 2) : fb;
  }
  if (tid < 8)  flags[tid] = 0;
  if (tid >= 8 && tid < 16) done[tid-8] = 0;
  __syncthreads();

  volatile int* vflags = flags;
  volatile int* vdone  = done;
  float* ringf = &ring[0][0][0];

  if (wid == 6){
    // ---------------- producer ----------------
    const float* bp8[8];
    #pragma unroll
    for (int r=0;r<8;r++){
      int mat  = r>>2;
      int irow = ((r*8)&31) + (lane>>3);
      bp8[r] = (mat ? w3 : w1) + (size_t)e*IDIM*HDIM + (size_t)(ibase+irow)*HDIM
             + (((lane&7)^(lane>>3))<<2);   // 16B-chunk XOR swizzle, *4 floats
    }
    for (int j=0;j<NS;++j){
      if (j>=8){
        for(;;){
          int mn = vdone[0];
          mn = min(mn, vdone[1]); mn = min(mn, vdone[2]);
          mn = min(mn, vdone[3]); mn = min(mn, vdone[4]); mn = min(mn, vdone[5]);
          if (mn >= j-7) break;
          __builtin_amdgcn_s_sleep(1);
        }
        CFENCE();
      }
      float* dst = ringf + (j&7)*2048;
      const int ko = j*32;
      #pragma unroll
      for (int r=0;r<8;r++) gload_lds16(bp8[r] + ko, dst + r*256);
      if (j>=3){
        WAITV(24); CFENCE();
        if (lane==0) vflags[(j-3)&7] = j-2;
      }
    }
    WAITV(16); CFENCE(); if (lane==0) vflags[(NS-3)&7] = NS-2;
    WAITV(8);  CFENCE(); if (lane==0) vflags[(NS-2)&7] = NS-1;
    WAITV(0);  CFENCE(); if (lane==0) vflags[(NS-1)&7] = NS;
  } else {
    // ---------------- consumer (wid 0..5): 64 rows each ----------------
    int q = lane>>4;
    const ushort* arow[4];
    #pragma unroll
    for (int m=0;m<4;m++){
      int row = wid*64 + m*16 + (lane&15);
      arow[m] = xb + (size_t)toks[row]*HDIM + q*8;
    }
    f32x4 accg[4][2], accu[4][2];
    #pragma unroll
    for (int m=0;m<4;m++)
      #pragma unroll
      for (int n=0;n<2;n++){ accg[m][n]=(f32x4){0,0,0,0}; accu[m][n]=(f32x4){0,0,0,0}; }

    bf16x8 aC[4];
    #pragma unroll
    for (int m=0;m<4;m++) aC[m] = *(const bf16x8*)(arow[m]);

    for (int j=0;j<NS;++j){
      while (vflags[j&7] < j+1) __builtin_amdgcn_s_sleep(1);
      CFENCE();
      __builtin_amdgcn_sched_barrier(0);
      const float* S = ringf + (j&7)*2048;
      #pragma unroll
      for (int mat=0;mat<2;mat++)
        #pragma unroll
        for (int nf=0;nf<2;nf++){
          int row = mat*32 + nf*16 + (lane&15);
          int p0  = (2*q) ^ (row&7);
          const float* R = S + row*32;
          f32x4 x1 = *(const f32x4*)(R + p0*4);
          f32x4 x2 = *(const f32x4*)(R + (p0^1)*4);
          uint4 uu; uu.x=pack_bf2(x1[0],x1[1]); uu.y=pack_bf2(x1[2],x1[3]);
          uu.z=pack_bf2(x2[0],x2[1]); uu.w=pack_bf2(x2[2],x2[3]);
          bf16x8 b = *reinterpret_cast<bf16x8*>(&uu);
          if (mat==0){
            #pragma unroll
            for (int m=0;m<4;m++) accg[m][nf] = __builtin_amdgcn_mfma_f32_16x16x32_bf16(aC[m], b, accg[m][nf], 0,0,0);
          } else {
            #pragma unroll
            for (int m=0;m<4;m++) accu[m][nf] = __builtin_amdgcn_mfma_f32_16x16x32_bf16(aC[m], b, accu[m][nf], 0,0,0);
          }
        }
      if (j+1 < NS){
        #pragma unroll
        for (int m=0;m<4;m++) aC[m] = *(const bf16x8*)(arow[m] + (j+1)*32);
      }
      if (lane==0) vdone[wid] = j+1;
    }

    int nval = ne - m0; if (nval > MTILE) nval = MTILE;
    #pragma unroll
    for (int m=0;m<4;m++)
      #pragma unroll
      for (int nf=0;nf<2;nf++)
        #pragma unroll
        for (int r=0;r<4;r++){
          int row = wid*64 + m*16 + (lane>>4)*4 + r;
          if (row < nval){
            float g = accg[m][nf][r], u = accu[m][nf][r];
            float sval = g / (1.f + __expf(-g)) * u;
            act[(size_t)(off0+m0+row)*IDIM + ibase + nf*16 + (lane&15)] = f2bf(sval);
          }
        }
  }
}

// ---------------- down GEMM ----------------
// M=384 x N=64, K=768 = 24 ring slots of 32. Same producer-consumer structure.
__global__ __launch_bounds__(448,4) void k_down(const ushort* __restrict__ act,
    const float* __restrict__ w2, const int* __restrict__ offsets,
    const int* __restrict__ mtE, const int* __restrict__ mtM0, const int* __restrict__ nmt,
    float* __restrict__ pout){
  const int NS = 24;
  int bi  = blockIdx.x;               // 1024
  int xcd = bi & 7, j0 = bi >> 3;
  int mti = (j0>>4)*8 + xcd;
  int ht  = j0 & 15;
  if (mti >= nmt[0]) return;
  int e    = mtE[mti];
  int m0   = mtM0[mti];
  int off0 = offsets[e], ne = offsets[e+1]-off0;
  int hbase = ht*64;

  __shared__ float ring[8][64][32];
  __shared__ int flags[8];
  __shared__ int done[8];

  int tid = threadIdx.x, wid = tid>>6, lane = tid&63;
  if (tid < 8)  flags[tid] = 0;
  if (tid >= 8 && tid < 16) done[tid-8] = 0;
  __syncthreads();

  volatile int* vflags = flags;
  volatile int* vdone  = done;
  float* ringf = &ring[0][0][0];

  if (wid == 6){
    const float* bp8[8];
    #pragma unroll
    for (int r=0;r<8;r++){
      int irow = r*8 + (lane>>3);
      bp8[r] = w2 + (size_t)e*HDIM*IDIM + (size_t)(hbase+irow)*IDIM
             + (((lane&7)^(lane>>3))<<2);
    }
    for (int j=0;j<NS;++j){
      if (j>=8){
        for(;;){
          int mn = vdone[0];
          mn = min(mn, vdone[1]); mn = min(mn, vdone[2]);
          mn = min(mn, vdone[3]); mn = min(mn, vdone[4]); mn = min(mn, vdone[5]);
          if (mn >= j-7) break;
          __builtin_amdgcn_s_sleep(1);
        }
        CFENCE();
      }
      float* dst = ringf + (j&7)*2048;
      const int ko = j*32;
      #pragma unroll
      for (int r=0;r<8;r++) gload_lds16(bp8[r] + ko, dst + r*256);
      if (j>=3){
        WAITV(24); CFENCE();
        if (lane==0) vflags[(j-3)&7] = j-2;
      }
    }
    WAITV(16); CFENCE(); if (lane==0) vflags[(NS-3)&7] = NS-2;
    WAITV(8);  CFENCE(); if (lane==0) vflags[(NS-2)&7] = NS-1;
    WAITV(0);  CFENCE(); if (lane==0) vflags[(NS-1)&7] = NS;
  } else {
    int q = lane>>4;
    const ushort* arow[4];
    #pragma unroll
    for (int m=0;m<4;m++){
      int row = m0 + wid*64 + m*16 + (lane&15);
      row = (row < ne) ? row : (ne-1);
      arow[m] = act + (size_t)(off0+row)*IDIM + q*8;
    }
    f32x4 acc[4][4];
    #pragma unroll
    for (int m=0;m<4;m++)
      #pragma unroll
      for (int n=0;n<4;n++) acc[m][n]=(f32x4){0,0,0,0};

    bf16x8 aC[4];
    #pragma unroll
    for (int m=0;m<4;m++) aC[m] = *(const bf16x8*)(arow[m]);

    for (int j=0;j<NS;++j){
      while (vflags[j&7] < j+1) __builtin_amdgcn_s_sleep(1);
      CFENCE();
      __builtin_amdgcn_sched_barrier(0);
      const float* S = ringf + (j&7)*2048;
      #pragma unroll
      for (int nf=0;nf<4;nf++){
        int row = nf*16 + (lane&15);
        int p0  = (2*q) ^ (row&7);
        const float* R = S + row*32;
        f32x4 x1 = *(const f32x4*)(R + p0*4);
        f32x4 x2 = *(const f32x4*)(R + (p0^1)*4);
        uint4 uu; uu.x=pack_bf2(x1[0],x1[1]); uu.y=pack_bf2(x1[2],x1[3]);
        uu.z=pack_bf2(x2[0],x2[1]); uu.w=pack_bf2(x2[2],x2[3]);
        bf16x8 b = *reinterpret_cast<bf16x8*>(&uu);
        #pragma unroll
        for (int m=0;m<4;m++)
          acc[m][nf] = __builtin_amdgcn_mfma_f32_16x16x32_bf16(aC[m], b, acc[m][nf], 0,0,0);
      }
      if (j+1 < NS){
        #pragma unroll
        for (int m=0;m<4;m++) aC[m] = *(const bf16x8*)(arow[m] + (j+1)*32);
      }
      if (lane==0) vdone[wid] = j+1;
    }

    int nval = ne - m0; if (nval > MTILE) nval = MTILE;
    #pragma unroll
    for (int m=0;m<4;m++)
      #pragma unroll
      for (int nf=0;nf<4;nf++)
        #pragma unroll
        for (int r=0;r<4;r++){
          int row = wid*64 + m*16 + (lane>>4)*4 + r;
          if (row < nval)
            pout[(size_t)(off0+m0+row)*HDIM + hbase + nf*16 + (lane&15)] = acc[m][nf][r];
        }
  }
}

// ---------------- combine ----------------
__global__ __launch_bounds__(256) void k_combine(const float* __restrict__ pout,
    const int* __restrict__ tk_slot, const float* __restrict__ wv,
    float* __restrict__ out){
  int t = blockIdx.x;
  int c = threadIdx.x;
  float a0=0,a1=0,a2=0,a3=0;
  #pragma unroll
  for (int k=0;k<TOPK;k++){
    int slot = tk_slot[t*TOPK+k];
    float w  = wv[t*TOPK+k];
    float4 v = *(const float4*)(pout + (size_t)slot*HDIM + c*4);
    a0 = fmaf(w, v.x, a0); a1 = fmaf(w, v.y, a1);
    a2 = fmaf(w, v.z, a2); a3 = fmaf(w, v.w, a3);
  }
  float4 o; o.x=a0; o.y=a1; o.z=a2; o.w=a3;
  *(float4*)(out + (size_t)t*HDIM + c*4) = o;
}

extern "C" void kernel_launch(void* const* d_in, const int* in_sizes, int n_in,
                              void* d_out, int out_size, void* d_ws, size_t ws_size,
                              hipStream_t stream){
  const float* x  = (const float*)d_in[0];
  const float* gw = (const float*)d_in[1];
  const float* w1 = (const float*)d_in[2];
  const float* w3 = (const float*)d_in[3];
  const float* w2 = (const float*)d_in[4];
  float* out = (float*)d_out;

  char* ws = (char*)d_ws;
  size_t off = 0;
  ushort* xb   = (ushort*)(ws + off); off += (size_t)T_TOK*HDIM*2;
  ushort* act  = (ushort*)(ws + off); off += (size_t)NPAIR*IDIM*2;
  float*  pout = (float*) (ws + off); off += (size_t)NPAIR*HDIM*4;
  int* counts  = (int*)(ws + off); off += NEXP*4;
  int* cursor  = (int*)(ws + off); off += NEXP*4;
  int* offsets = (int*)(ws + off); off += (NEXP+1)*4;
  int* mtE     = (int*)(ws + off); off += MAXMT*4;
  int* mtM0    = (int*)(ws + off); off += MAXMT*4;
  int* nmt     = (int*)(ws + off); off += 4;
  off = (off + 255) & ~(size_t)255;
  int*   ei      = (int*)  (ws + off); off += (size_t)NPAIR*4;
  float* wvp     = (float*)(ws + off); off += (size_t)NPAIR*4;
  int*   slot_tk = (int*)  (ws + off); off += (size_t)NPAIR*4;
  int*   tk_slot = (int*)  (ws + off); off += (size_t)NPAIR*4;

  hipMemsetAsync(counts, 0, 2*NEXP*4, stream);

  k_convert_x<<<T_TOK*HDIM/1024, 256, 0, stream>>>(x, xb);
  k_router<<<T_TOK/4, 256, 0, stream>>>(x, gw, ei, wvp, counts);
  k_offsets<<<1, 64, 0, stream>>>(counts, offsets, mtE, mtM0, nmt);
  k_scatter<<<NPAIR/256, 256, 0, stream>>>(ei, offsets, cursor, slot_tk, tk_slot);
  k_gateup<<<1536, 448, 0, stream>>>(xb, w1, w3, offsets, slot_tk, mtE, mtM0, nmt, act);
  k_down<<<1024, 448, 0, stream>>>(act, w2, offsets, mtE, mtM0, nmt, pout);
  k_combine<<<T_TOK, 256, 0, stream>>>(pout, tk_slot, wvp, out);
}